// Round 1
// baseline (1303.027 us; speedup 1.0000x reference)
//
#include <hip/hip_runtime.h>
#include <hip/hip_bf16.h>
#include <math.h>

#define SLOPE 0.01f
#define EPS_LN 1e-5f

typedef __hip_bfloat16 bf16;
typedef __attribute__((ext_vector_type(8))) short short8;
typedef __attribute__((ext_vector_type(4))) float f32x4;

__device__ __forceinline__ float leakyf(float x) { return x < 0.f ? SLOPE * x : x; }

__device__ __forceinline__ void gload_lds16(const void* g, void* l) {
    __builtin_amdgcn_global_load_lds(
        (const __attribute__((address_space(1))) void*)g,
        (__attribute__((address_space(3))) void*)l, 16, 0, 0);
}

// ---------------------------------------------------------------------------
// GEMM: Out[b][m][n] = sum_k A[b][m*ldA + k] * Bt[n][k]  (+bias, opt leaky)
// A is bf16 with row stride ldA (rows may overlap: conv-as-GEMM), Bt is bf16 [N][K].
// Tiles: BM=BN=128, BK=64. 256 threads = 4 waves, each wave owns 64x64.
// EPI: 0 = raw + bias (f32 out), 1 = bias + leaky (f32 out)
// ---------------------------------------------------------------------------
template <int EPI>
__global__ __launch_bounds__(256, 2) void gemm_bf16(
    const bf16* __restrict__ A, long sA, int ldA,
    const bf16* __restrict__ Bt,
    const float* __restrict__ bias,
    float* __restrict__ Out, long sO, int ldO, int K)
{
    __shared__ bf16 As[128][64];
    __shared__ bf16 Bs[128][64];
    const int b = blockIdx.z;
    const bf16* Ab = A + (long)b * sA + (long)blockIdx.y * 128 * ldA;
    const bf16* Bb = Bt + (long)blockIdx.x * 128 * K;
    const int tid = threadIdx.x;
    const int wave = tid >> 6, lane = tid & 63;
    const int moff = (wave >> 1) * 64, noff = (wave & 1) * 64;
    const int r16 = lane & 15, g4 = lane >> 4;

    f32x4 acc[4][4];
#pragma unroll
    for (int i = 0; i < 4; ++i)
#pragma unroll
        for (int j = 0; j < 4; ++j)
            acc[i][j] = (f32x4){0.f, 0.f, 0.f, 0.f};

    for (int k0 = 0; k0 < K; k0 += 64) {
        __syncthreads();
        // Stage A tile: 128 rows x 64 k (bf16) = 16KB = 1024 chunks of 16B.
        // LDS dest: wave-uniform base + lane*16 (HW). chunk = i*256 + tid.
#pragma unroll
        for (int i = 0; i < 4; ++i) {
            int chunk = i * 256 + tid;
            int row = chunk >> 3, kc = chunk & 7;
            gload_lds16(Ab + (long)row * ldA + (k0 + kc * 8),
                        (char*)(&As[0][0]) + (i * 256 + wave * 64) * 16);
        }
#pragma unroll
        for (int i = 0; i < 4; ++i) {
            int chunk = i * 256 + tid;
            int row = chunk >> 3, kc = chunk & 7;
            gload_lds16(Bb + (long)row * K + (k0 + kc * 8),
                        (char*)(&Bs[0][0]) + (i * 256 + wave * 64) * 16);
        }
        __syncthreads();
#pragma unroll
        for (int kk = 0; kk < 2; ++kk) {
            short8 af[4], bfr[4];
#pragma unroll
            for (int mi = 0; mi < 4; ++mi)
                af[mi] = *(const short8*)&As[moff + mi * 16 + r16][kk * 32 + g4 * 8];
#pragma unroll
            for (int ni = 0; ni < 4; ++ni)
                bfr[ni] = *(const short8*)&Bs[noff + ni * 16 + r16][kk * 32 + g4 * 8];
#pragma unroll
            for (int mi = 0; mi < 4; ++mi)
#pragma unroll
                for (int ni = 0; ni < 4; ++ni)
                    acc[mi][ni] = __builtin_amdgcn_mfma_f32_16x16x32_bf16(
                        af[mi], bfr[ni], acc[mi][ni], 0, 0, 0);
        }
    }

    float* Ob = Out + (long)b * sO;
#pragma unroll
    for (int mi = 0; mi < 4; ++mi) {
#pragma unroll
        for (int ni = 0; ni < 4; ++ni) {
            int col = blockIdx.x * 128 + noff + ni * 16 + r16;
            float bv = bias[col];
#pragma unroll
            for (int r = 0; r < 4; ++r) {
                int row = blockIdx.y * 128 + moff + mi * 16 + g4 * 4 + r;
                float v = acc[mi][ni][r] + bv;
                if (EPI == 1) v = leakyf(v);
                Ob[(long)row * ldO + col] = v;
            }
        }
    }
}

// ---------------------------------------------------------------------------
// feats f32 [B,1024,C] -> padded bf16 [B,1026,C] (zero rows 0 and 1025)
// ---------------------------------------------------------------------------
__global__ void pack_feats_k(const float* __restrict__ f, bf16* __restrict__ xp, int C)
{
    long idx = (long)blockIdx.x * 256 + threadIdx.x;
    long total = 16L * 1026 * C;
    if (idx >= total) return;
    int c = (int)(idx % C);
    long t = idx / C;
    int r = (int)(t % 1026);
    int b = (int)(t / 1026);
    float v = 0.f;
    if (r >= 1 && r <= 1024) v = f[((long)b * 1024 + (r - 1)) * C + c];
    xp[idx] = __float2bfloat16(v);
}

// Yraw f32 [B,1024,C] -> LN(stat)+leaky -> padded bf16 [B,1026,C]
__global__ void norm_pack_k(const float* __restrict__ y, const float2* __restrict__ stat,
                            bf16* __restrict__ xp, int C)
{
    long idx = (long)blockIdx.x * 256 + threadIdx.x;
    long total = 16L * 1026 * C;
    if (idx >= total) return;
    int c = (int)(idx % C);
    long t = idx / C;
    int r = (int)(t % 1026);
    int b = (int)(t / 1026);
    float v = 0.f;
    if (r >= 1 && r <= 1024) {
        float2 s = stat[b];
        float x = y[((long)b * 1024 + (r - 1)) * C + c];
        v = leakyf((x - s.x) * s.y);
    }
    xp[idx] = __float2bfloat16(v);
}

// cv3: Yraw f32 [B,1024,640] -> LN+leaky + feats -> Acat[:, :, 640:1280] bf16
__global__ void norm_addf_k(const float* __restrict__ y, const float2* __restrict__ stat,
                            const float* __restrict__ feats, bf16* __restrict__ acat)
{
    long idx = (long)blockIdx.x * 256 + threadIdx.x;
    long total = 16L * 1024 * 640;
    if (idx >= total) return;
    int c = (int)(idx % 640);
    int l = (int)((idx / 640) % 1024);
    int b = (int)(idx / (640L * 1024));
    float2 s = stat[b];
    float v = leakyf((y[idx] - s.x) * s.y) + feats[idx];
    acat[((long)b * 1024 + l) * 1280 + 640 + c] = __float2bfloat16(v);
}

// ---------------------------------------------------------------------------
// LN stats over [1024*C] per batch: two stages
// ---------------------------------------------------------------------------
__global__ void stats_part_k(const float* __restrict__ y, long Ntot, float2* __restrict__ part)
{
    int b = blockIdx.y, blk = blockIdx.x;
    const float* yb = y + (long)b * Ntot;
    long per = Ntot / 64;
    long base = (long)blk * per;
    float s = 0.f, q = 0.f;
    for (long i = threadIdx.x; i < per; i += 256) {
        float v = yb[base + i];
        s += v; q += v * v;
    }
    __shared__ float ss[256], qq[256];
    ss[threadIdx.x] = s; qq[threadIdx.x] = q;
    __syncthreads();
    for (int o = 128; o; o >>= 1) {
        if (threadIdx.x < o) { ss[threadIdx.x] += ss[threadIdx.x + o]; qq[threadIdx.x] += qq[threadIdx.x + o]; }
        __syncthreads();
    }
    if (threadIdx.x == 0) part[b * 64 + blk] = make_float2(ss[0], qq[0]);
}

__global__ void stats_fin_k(const float2* __restrict__ part, float2* __restrict__ stat, long Ntot)
{
    int b = blockIdx.x;
    float2 p = part[b * 64 + threadIdx.x];
    float s = p.x, q = p.y;
    for (int o = 32; o; o >>= 1) { s += __shfl_down(s, o); q += __shfl_down(q, o); }
    if (threadIdx.x == 0) {
        float m = s / (float)Ntot;
        float var = q / (float)Ntot - m * m;
        stat[b] = make_float2(m, rsqrtf(var + EPS_LN));
    }
}

// ---------------------------------------------------------------------------
// cp conv3: N=2 special case. One wave per (b,l): out = X[l-1..l+1,:] . w3[o,:]
// w3 repacked bf16 [2][3840]. Output sw f32 [B][2][1024].
// ---------------------------------------------------------------------------
__global__ void conv3cp_k(const bf16* __restrict__ xp, const bf16* __restrict__ w3,
                          const float* __restrict__ b3, float* __restrict__ sw)
{
    int wid = (int)((blockIdx.x * 256 + threadIdx.x) >> 6);
    int lane = threadIdx.x & 63;
    int b = wid >> 10, l = wid & 1023;
    const bf16* xr = xp + ((long)b * 1026 + l) * 1280;
    float a0 = 0.f, a1 = 0.f;
    for (int k = lane; k < 3840; k += 64) {
        float x = __bfloat162float(xr[k]);
        a0 += x * __bfloat162float(w3[k]);
        a1 += x * __bfloat162float(w3[3840 + k]);
    }
    for (int o = 32; o; o >>= 1) { a0 += __shfl_down(a0, o); a1 += __shfl_down(a1, o); }
    if (lane == 0) {
        sw[b * 2048 + l] = a0 + b3[0];
        sw[b * 2048 + 1024 + l] = a1 + b3[1];
    }
}

// ---------------------------------------------------------------------------
// cp post: LN over [2,1024] + leaky + 2x softmax -> stdb (=102.4*s), wb
// One block per b.
// ---------------------------------------------------------------------------
__global__ __launch_bounds__(256) void cp_post_k(const float* __restrict__ sw,
                                                 float* __restrict__ stdb,
                                                 float* __restrict__ wb)
{
    int b = blockIdx.x, tid = threadIdx.x;
    __shared__ float s0[1024], s1[1024], red[256];
    const float* p = sw + b * 2048;
    float s = 0.f, q = 0.f;
    for (int l = tid; l < 1024; l += 256) {
        float v0 = p[l], v1 = p[1024 + l];
        s0[l] = v0; s1[l] = v1;
        s += v0 + v1; q += v0 * v0 + v1 * v1;
    }
    red[tid] = s; __syncthreads();
    for (int o = 128; o; o >>= 1) { if (tid < o) red[tid] += red[tid + o]; __syncthreads(); }
    float mean = red[0] / 2048.f; __syncthreads();
    red[tid] = q; __syncthreads();
    for (int o = 128; o; o >>= 1) { if (tid < o) red[tid] += red[tid + o]; __syncthreads(); }
    float inv = rsqrtf(red[0] / 2048.f - mean * mean + EPS_LN); __syncthreads();
    for (int l = tid; l < 1024; l += 256) {
        s0[l] = leakyf((s0[l] - mean) * inv);
        s1[l] = leakyf((s1[l] - mean) * inv);
    }
    __syncthreads();
    // softmax ch0 -> std = 102.4 * s
    float mx = -1e30f;
    for (int l = tid; l < 1024; l += 256) mx = fmaxf(mx, s0[l]);
    red[tid] = mx; __syncthreads();
    for (int o = 128; o; o >>= 1) { if (tid < o) red[tid] = fmaxf(red[tid], red[tid + o]); __syncthreads(); }
    mx = red[0]; __syncthreads();
    float se = 0.f;
    for (int l = tid; l < 1024; l += 256) { float e = __expf(s0[l] - mx); s0[l] = e; se += e; }
    red[tid] = se; __syncthreads();
    for (int o = 128; o; o >>= 1) { if (tid < o) red[tid] += red[tid + o]; __syncthreads(); }
    float rs = 1.f / red[0]; __syncthreads();
    for (int l = tid; l < 1024; l += 256) stdb[b * 1024 + l] = 102.4f * s0[l] * rs;
    // softmax ch1 -> w
    mx = -1e30f;
    for (int l = tid; l < 1024; l += 256) mx = fmaxf(mx, s1[l]);
    red[tid] = mx; __syncthreads();
    for (int o = 128; o; o >>= 1) { if (tid < o) red[tid] = fmaxf(red[tid], red[tid + o]); __syncthreads(); }
    mx = red[0]; __syncthreads();
    se = 0.f;
    for (int l = tid; l < 1024; l += 256) { float e = __expf(s1[l] - mx); s1[l] = e; se += e; }
    red[tid] = se; __syncthreads();
    for (int o = 128; o; o >>= 1) { if (tid < o) red[tid] += red[tid + o]; __syncthreads(); }
    rs = 1.f / red[0]; __syncthreads();
    for (int l = tid; l < 1024; l += 256) wb[b * 1024 + l] = s1[l] * rs;
}

// ---------------------------------------------------------------------------
// pooling: out_sa[b,i,:] = sum_j exp(-(i-j)^2*inv_i)*w_j*feats[b,j,:] + feats[b,i,:]
// radius-pruned at exp < 1e-5. Block = (i, b), 256 threads over d (640 = 256+256+128).
// Writes Acat[:, :, 0:640] bf16.
// ---------------------------------------------------------------------------
__global__ __launch_bounds__(256) void pool_k(const float* __restrict__ feats,
                                              const float* __restrict__ stdb,
                                              const float* __restrict__ wb,
                                              bf16* __restrict__ acat)
{
    int i = blockIdx.x, b = blockIdx.y, tid = threadIdx.x;
    float sd = stdb[b * 1024 + i];
    float den = 1e-5f + 2.f * sd * sd;
    float inv = 1.f / den;
    int R = (int)sqrtf(11.5129255f * den) + 1;  // exp cutoff at 1e-5
    int jlo = max(0, i - R), jhi = min(1023, i + R);
    __shared__ float cj[256];
    float a0 = 0.f, a1 = 0.f, a2 = 0.f;
    const float* fb = feats + (long)b * 1024 * 640;
    for (int j0 = jlo; j0 <= jhi; j0 += 256) {
        int j = j0 + tid;
        float c = 0.f;
        if (j <= jhi) {
            float d = (float)(j - i);
            c = __expf(-d * d * inv) * wb[b * 1024 + j];
        }
        __syncthreads();
        cj[tid] = c;
        __syncthreads();
        int lim = min(256, jhi - j0 + 1);
        for (int t = 0; t < lim; ++t) {
            float cc = cj[t];
            const float* fr = fb + (long)(j0 + t) * 640;
            a0 += cc * fr[tid];
            a1 += cc * fr[tid + 256];
            if (tid < 128) a2 += cc * fr[tid + 512];
        }
    }
    long obase = ((long)b * 1024 + i) * 1280;
    long fbase = ((long)b * 1024 + i) * 640;
    acat[obase + tid] = __float2bfloat16(a0 + feats[fbase + tid]);
    acat[obase + tid + 256] = __float2bfloat16(a1 + feats[fbase + tid + 256]);
    if (tid < 128) acat[obase + tid + 512] = __float2bfloat16(a2 + feats[fbase + tid + 512]);
}

// ---------------------------------------------------------------------------
// weight repack: w f32 [CO][CI][3] -> Bt bf16 [CO][3*CI], k = t*CI + ci
// ---------------------------------------------------------------------------
__global__ void repack_w_k(const float* __restrict__ w, bf16* __restrict__ bt, int CO, int CI)
{
    long idx = (long)blockIdx.x * 256 + threadIdx.x;
    long total = (long)CO * CI * 3;
    if (idx >= total) return;
    int K3 = 3 * CI;
    int o = (int)(idx / K3);
    int k = (int)(idx % K3);
    int t = k / CI, ci = k % CI;
    bt[idx] = __float2bfloat16(w[(long)o * CI * 3 + ci * 3 + t]);
}

__global__ void cast_bf16_k(const float* __restrict__ w, bf16* __restrict__ o, long n)
{
    long idx = (long)blockIdx.x * 256 + threadIdx.x;
    if (idx < n) o[idx] = __float2bfloat16(w[idx]);
}

// ---------------------------------------------------------------------------
extern "C" void kernel_launch(void* const* d_in, const int* in_sizes, int n_in,
                              void* d_out, int out_size, void* d_ws, size_t ws_size,
                              hipStream_t stream)
{
    const float* feats = (const float*)d_in[0];
    const float* cp_w1 = (const float*)d_in[1];
    const float* cp_b1 = (const float*)d_in[2];
    const float* cp_w2 = (const float*)d_in[3];
    const float* cp_b2 = (const float*)d_in[4];
    const float* cp_w3 = (const float*)d_in[5];
    const float* cp_b3 = (const float*)d_in[6];
    const float* cv_w1 = (const float*)d_in[7];
    const float* cv_b1 = (const float*)d_in[8];
    const float* cv_w2 = (const float*)d_in[9];
    const float* cv_b2 = (const float*)d_in[10];
    const float* cv_w3 = (const float*)d_in[11];
    const float* cv_b3 = (const float*)d_in[12];
    const float* mlp_w = (const float*)d_in[13];
    const float* mlp_b = (const float*)d_in[14];
    float* out = (float*)d_out;

    char* ws = (char*)d_ws;
    size_t off = 0;
    auto alloc = [&](size_t bytes) -> char* {
        char* p = ws + off;
        off += (bytes + 255) & ~(size_t)255;
        return p;
    };
    bf16* XpadF = (bf16*)alloc(16L * 1026 * 640 * 2);
    bf16* Xpad2 = (bf16*)alloc(16L * 1026 * 1280 * 2);
    float* Yraw = (float*)alloc(16L * 1024 * 1280 * 4);
    bf16* Acat = (bf16*)alloc(16L * 1024 * 1280 * 2);
    bf16* Bcp1 = (bf16*)alloc(1280L * 1920 * 2);
    bf16* Bcp2 = (bf16*)alloc(1280L * 3840 * 2);
    bf16* Bcp3 = (bf16*)alloc(2L * 3840 * 2);
    bf16* Bcv1 = (bf16*)alloc(1280L * 1920 * 2);
    bf16* Bcv2 = (bf16*)alloc(1280L * 3840 * 2);
    bf16* Bcv3 = (bf16*)alloc(640L * 3840 * 2);
    bf16* Bmlp = (bf16*)alloc(640L * 1280 * 2);
    float* swb = (float*)alloc(16L * 2048 * 4);
    float* stdb = (float*)alloc(16L * 1024 * 4);
    float* wbf = (float*)alloc(16L * 1024 * 4);
    float2* part = (float2*)alloc(16L * 64 * 8);
    float2* stat = (float2*)alloc(16L * 8);
    (void)ws_size; (void)in_sizes; (void)n_in; (void)out_size;

    const long NF = 16L * 1026 * 640;
    const long N2 = 16L * 1026 * 1280;
    const long NA = 16L * 1024 * 640;
    const long N1280 = 1024L * 1280, N640 = 1024L * 640;

    // pack + repacks
    pack_feats_k<<<(NF + 255) / 256, 256, 0, stream>>>(feats, XpadF, 640);
    repack_w_k<<<(1280L * 640 * 3 + 255) / 256, 256, 0, stream>>>(cp_w1, Bcp1, 1280, 640);
    repack_w_k<<<(1280L * 1280 * 3 + 255) / 256, 256, 0, stream>>>(cp_w2, Bcp2, 1280, 1280);
    repack_w_k<<<(2L * 1280 * 3 + 255) / 256, 256, 0, stream>>>(cp_w3, Bcp3, 2, 1280);
    repack_w_k<<<(1280L * 640 * 3 + 255) / 256, 256, 0, stream>>>(cv_w1, Bcv1, 1280, 640);
    repack_w_k<<<(1280L * 1280 * 3 + 255) / 256, 256, 0, stream>>>(cv_w2, Bcv2, 1280, 1280);
    repack_w_k<<<(640L * 1280 * 3 + 255) / 256, 256, 0, stream>>>(cv_w3, Bcv3, 640, 1280);
    cast_bf16_k<<<(640L * 1280 + 255) / 256, 256, 0, stream>>>(mlp_w, Bmlp, 640L * 1280);

    // ---- cp branch ----
    gemm_bf16<0><<<dim3(10, 8, 16), 256, 0, stream>>>(XpadF, 1026L * 640, 640, Bcp1, cp_b1,
                                                      Yraw, N1280, 1280, 1920);
    stats_part_k<<<dim3(64, 16), 256, 0, stream>>>(Yraw, N1280, part);
    stats_fin_k<<<16, 64, 0, stream>>>(part, stat, N1280);
    norm_pack_k<<<(N2 + 255) / 256, 256, 0, stream>>>(Yraw, stat, Xpad2, 1280);
    gemm_bf16<0><<<dim3(10, 8, 16), 256, 0, stream>>>(Xpad2, 1026L * 1280, 1280, Bcp2, cp_b2,
                                                      Yraw, N1280, 1280, 3840);
    stats_part_k<<<dim3(64, 16), 256, 0, stream>>>(Yraw, N1280, part);
    stats_fin_k<<<16, 64, 0, stream>>>(part, stat, N1280);
    norm_pack_k<<<(N2 + 255) / 256, 256, 0, stream>>>(Yraw, stat, Xpad2, 1280);
    conv3cp_k<<<4096, 256, 0, stream>>>(Xpad2, Bcp3, cp_b3, swb);
    cp_post_k<<<16, 256, 0, stream>>>(swb, stdb, wbf);
    pool_k<<<dim3(1024, 16), 256, 0, stream>>>(feats, stdb, wbf, Acat);

    // ---- cv branch ----
    gemm_bf16<0><<<dim3(10, 8, 16), 256, 0, stream>>>(XpadF, 1026L * 640, 640, Bcv1, cv_b1,
                                                      Yraw, N1280, 1280, 1920);
    stats_part_k<<<dim3(64, 16), 256, 0, stream>>>(Yraw, N1280, part);
    stats_fin_k<<<16, 64, 0, stream>>>(part, stat, N1280);
    norm_pack_k<<<(N2 + 255) / 256, 256, 0, stream>>>(Yraw, stat, Xpad2, 1280);
    gemm_bf16<0><<<dim3(10, 8, 16), 256, 0, stream>>>(Xpad2, 1026L * 1280, 1280, Bcv2, cv_b2,
                                                      Yraw, N1280, 1280, 3840);
    stats_part_k<<<dim3(64, 16), 256, 0, stream>>>(Yraw, N1280, part);
    stats_fin_k<<<16, 64, 0, stream>>>(part, stat, N1280);
    norm_pack_k<<<(N2 + 255) / 256, 256, 0, stream>>>(Yraw, stat, Xpad2, 1280);
    gemm_bf16<0><<<dim3(5, 8, 16), 256, 0, stream>>>(Xpad2, 1026L * 1280, 1280, Bcv3, cv_b3,
                                                     Yraw, N640, 640, 3840);
    stats_part_k<<<dim3(64, 16), 256, 0, stream>>>(Yraw, N640, part);
    stats_fin_k<<<16, 64, 0, stream>>>(part, stat, N640);
    norm_addf_k<<<(NA + 255) / 256, 256, 0, stream>>>(Yraw, stat, feats, Acat);

    // ---- MLP ----
    gemm_bf16<1><<<dim3(5, 8, 16), 256, 0, stream>>>(Acat, N1280, 1280, Bmlp, mlp_b,
                                                     out, N640, 640, 1280);
}

// Round 2
// 855.310 us; speedup vs baseline: 1.5235x; 1.5235x over previous
//
#include <hip/hip_runtime.h>
#include <hip/hip_bf16.h>
#include <math.h>

#define SLOPE 0.01f
#define EPS_LN 1e-5f

typedef __hip_bfloat16 bf16;
typedef __attribute__((ext_vector_type(8))) short short8;
typedef __attribute__((ext_vector_type(4))) float f32x4;

__device__ __forceinline__ float leakyf(float x) { return x < 0.f ? SLOPE * x : x; }

__device__ __forceinline__ float b2f(short s) {
    unsigned u = ((unsigned)(unsigned short)s) << 16;
    return __builtin_bit_cast(float, u);
}
__device__ __forceinline__ short f2b(float f) {
    __hip_bfloat16 h = __float2bfloat16(f);
    return *(short*)&h;
}

__device__ __forceinline__ void gload_lds16(const void* g, void* l) {
    __builtin_amdgcn_global_load_lds(
        (const __attribute__((address_space(1))) void*)g,
        (__attribute__((address_space(3))) void*)l, 16, 0, 0);
}

// ---------------------------------------------------------------------------
// GEMM: Out[b][m][n] = sum_k A[b][m*ldA + k] * Bt[n][k]  (+bias)
// EPI 0: out bf16 + per-batch sum/sumsq atomics (for fused LN stats)
// EPI 1: out f32, bias + leaky (final MLP)
// 128x128 tile, BK=64, 4 waves. T2 LDS swizzle: global source pre-swizzled
// (chunk p at row r holds global chunk p^(r&7)); ds_read applies same XOR.
// T1: XCD-chunked block swizzle on a 1D grid (nwg % 8 == 0 always here).
// ---------------------------------------------------------------------------
template <int EPI>
__global__ __launch_bounds__(256, 2) void gemm_bf16(
    const bf16* __restrict__ A, long sA, int ldA,
    const bf16* __restrict__ Bt,
    const float* __restrict__ bias,
    void* __restrict__ Outv, long sO, int ldO, int K,
    int gx, int gy, float2* __restrict__ stats)
{
    __shared__ bf16 As[128][64];
    __shared__ bf16 Bs[128][64];

    // XCD-aware swizzle: contiguous work chunks per XCD (bijective: nwg%8==0)
    const int nwg = gridDim.x;
    const int wid = (blockIdx.x & 7) * (nwg >> 3) + (blockIdx.x >> 3);
    const int bx = wid % gx;
    const int by = (wid / gx) % gy;
    const int bz = wid / (gx * gy);

    const bf16* Ab = A + (long)bz * sA + (long)by * 128 * ldA;
    const bf16* Bb = Bt + (long)bx * 128 * K;
    const int tid = threadIdx.x;
    const int wave = tid >> 6, lane = tid & 63;
    const int moff = (wave >> 1) * 64, noff = (wave & 1) * 64;
    const int r16 = lane & 15, g4 = lane >> 4;
    const int r7 = r16 & 7;

    f32x4 acc[4][4];
#pragma unroll
    for (int i = 0; i < 4; ++i)
#pragma unroll
        for (int j = 0; j < 4; ++j)
            acc[i][j] = (f32x4){0.f, 0.f, 0.f, 0.f};

    for (int k0 = 0; k0 < K; k0 += 64) {
        __syncthreads();
        // stage with pre-swizzled global source: phys chunk p of row r gets
        // global chunk kc = p ^ (r&7); LDS dest stays linear (HW requirement).
#pragma unroll
        for (int i = 0; i < 4; ++i) {
            int chunk = i * 256 + tid;
            int row = chunk >> 3;
            int kc = (chunk ^ (chunk >> 3)) & 7;
            gload_lds16(Ab + (long)row * ldA + (k0 + kc * 8),
                        (char*)(&As[0][0]) + (i * 256 + wave * 64) * 16);
        }
#pragma unroll
        for (int i = 0; i < 4; ++i) {
            int chunk = i * 256 + tid;
            int row = chunk >> 3;
            int kc = (chunk ^ (chunk >> 3)) & 7;
            gload_lds16(Bb + (long)row * K + (k0 + kc * 8),
                        (char*)(&Bs[0][0]) + (i * 256 + wave * 64) * 16);
        }
        __syncthreads();
#pragma unroll
        for (int kk = 0; kk < 2; ++kk) {
            short8 af[4], bfr[4];
#pragma unroll
            for (int mi = 0; mi < 4; ++mi)
                af[mi] = *(const short8*)&As[moff + mi * 16 + r16][((kk * 4 + g4) ^ r7) * 8];
#pragma unroll
            for (int ni = 0; ni < 4; ++ni)
                bfr[ni] = *(const short8*)&Bs[noff + ni * 16 + r16][((kk * 4 + g4) ^ r7) * 8];
#pragma unroll
            for (int mi = 0; mi < 4; ++mi)
#pragma unroll
                for (int ni = 0; ni < 4; ++ni)
                    acc[mi][ni] = __builtin_amdgcn_mfma_f32_16x16x32_bf16(
                        af[mi], bfr[ni], acc[mi][ni], 0, 0, 0);
        }
    }

    float s = 0.f, q = 0.f;
#pragma unroll
    for (int mi = 0; mi < 4; ++mi) {
#pragma unroll
        for (int ni = 0; ni < 4; ++ni) {
            int col = bx * 128 + noff + ni * 16 + r16;
            float bv = bias[col];
#pragma unroll
            for (int r = 0; r < 4; ++r) {
                int row = by * 128 + moff + mi * 16 + g4 * 4 + r;
                float v = acc[mi][ni][r] + bv;
                if (EPI == 1) {
                    ((float*)Outv)[(long)bz * sO + (long)row * ldO + col] = leakyf(v);
                } else {
                    ((bf16*)Outv)[(long)bz * sO + (long)row * ldO + col] = __float2bfloat16(v);
                    s += v; q += v * v;
                }
            }
        }
    }
    if (EPI == 0) {
        __syncthreads();
        float* red = (float*)&As[0][0];
        float* red2 = red + 256;
        red[tid] = s; red2[tid] = q;
        __syncthreads();
        for (int o = 128; o; o >>= 1) {
            if (tid < o) { red[tid] += red[tid + o]; red2[tid] += red2[tid + o]; }
            __syncthreads();
        }
        if (tid == 0) {
            atomicAdd(&stats[bz].x, red[0]);
            atomicAdd(&stats[bz].y, red2[0]);
        }
    }
}

// ---------------------------------------------------------------------------
__global__ void zero_stats_k(float2* s) {
    if (threadIdx.x < 16) s[threadIdx.x] = make_float2(0.f, 0.f);
}

__global__ void fin_k(const float2* __restrict__ acc, float2* __restrict__ stat, float invN) {
    int b = threadIdx.x;
    if (b < 16) {
        float m = acc[b].x * invN;
        float var = acc[b].y * invN - m * m;
        stat[b] = make_float2(m, rsqrtf(var + EPS_LN));
    }
}

// ---------------------------------------------------------------------------
// feats f32 [B,1024,C] -> padded bf16 [B,1026,C] (zero rows 0,1025). 8/thread.
// ---------------------------------------------------------------------------
__global__ void pack_feats_v_k(const float* __restrict__ f, bf16* __restrict__ xp, int C)
{
    long i8 = (long)blockIdx.x * 256 + threadIdx.x;
    long total8 = 16L * 1026 * C / 8;
    if (i8 >= total8) return;
    long e = i8 * 8;
    int c = (int)(e % C);
    long t = e / C;
    int r = (int)(t % 1026);
    int b = (int)(t / 1026);
    short8 o;
    if (r == 0 || r == 1025) {
#pragma unroll
        for (int j = 0; j < 8; ++j) o[j] = 0;
    } else {
        const float* src = f + ((long)b * 1024 + (r - 1)) * C + c;
        f32x4 v0 = *(const f32x4*)src;
        f32x4 v1 = *(const f32x4*)(src + 4);
#pragma unroll
        for (int j = 0; j < 4; ++j) { o[j] = f2b(v0[j]); o[j + 4] = f2b(v1[j]); }
    }
    *(short8*)(xp + e) = o;
}

// Y bf16 [B,1024,C] -> leaky(LN) -> padded bf16 [B,1026,C]. 8/thread.
__global__ void norm_pack_v_k(const bf16* __restrict__ y, const float2* __restrict__ stat,
                              bf16* __restrict__ xp, int C)
{
    long i8 = (long)blockIdx.x * 256 + threadIdx.x;
    long total8 = 16L * 1026 * C / 8;
    if (i8 >= total8) return;
    long e = i8 * 8;
    int c = (int)(e % C);
    long t = e / C;
    int r = (int)(t % 1026);
    int b = (int)(t / 1026);
    short8 o;
    if (r == 0 || r == 1025) {
#pragma unroll
        for (int j = 0; j < 8; ++j) o[j] = 0;
    } else {
        float2 st = stat[b];
        short8 v = *(const short8*)(y + ((long)b * 1024 + (r - 1)) * C + c);
#pragma unroll
        for (int j = 0; j < 8; ++j)
            o[j] = f2b(leakyf((b2f(v[j]) - st.x) * st.y));
    }
    *(short8*)(xp + e) = o;
}

// cv3: Y bf16 [B,1024,640] -> leaky(LN) + feats -> Acat[:, :, 640:1280]. 8/thread.
__global__ void norm_addf_v_k(const bf16* __restrict__ y, const float2* __restrict__ stat,
                              const float* __restrict__ feats, bf16* __restrict__ acat)
{
    long i8 = (long)blockIdx.x * 256 + threadIdx.x;
    long total8 = 16L * 1024 * 640 / 8;
    if (i8 >= total8) return;
    long e = i8 * 8;
    int c = (int)(e % 640);
    int l = (int)((e / 640) % 1024);
    int b = (int)(e / (640L * 1024));
    float2 st = stat[b];
    short8 v = *(const short8*)(y + e);
    f32x4 f0 = *(const f32x4*)(feats + e);
    f32x4 f1 = *(const f32x4*)(feats + e + 4);
    short8 o;
#pragma unroll
    for (int j = 0; j < 4; ++j) {
        o[j] = f2b(leakyf((b2f(v[j]) - st.x) * st.y) + f0[j]);
        o[j + 4] = f2b(leakyf((b2f(v[j + 4]) - st.x) * st.y) + f1[j]);
    }
    *(short8*)(acat + ((long)b * 1024 + l) * 1280 + 640 + c) = o;
}

// ---------------------------------------------------------------------------
// cp conv3 (N=2): one wave per (b,l). w3 repacked bf16 [2][3840].
// ---------------------------------------------------------------------------
__global__ void conv3cp_k(const bf16* __restrict__ xp, const bf16* __restrict__ w3,
                          const float* __restrict__ b3, float* __restrict__ sw)
{
    int wid = (int)((blockIdx.x * 256 + threadIdx.x) >> 6);
    int lane = threadIdx.x & 63;
    int b = wid >> 10, l = wid & 1023;
    const bf16* xr = xp + ((long)b * 1026 + l) * 1280;
    float a0 = 0.f, a1 = 0.f;
    for (int k = lane; k < 3840; k += 64) {
        float x = __bfloat162float(xr[k]);
        a0 += x * __bfloat162float(w3[k]);
        a1 += x * __bfloat162float(w3[3840 + k]);
    }
    for (int o = 32; o; o >>= 1) { a0 += __shfl_down(a0, o); a1 += __shfl_down(a1, o); }
    if (lane == 0) {
        sw[b * 2048 + l] = a0 + b3[0];
        sw[b * 2048 + 1024 + l] = a1 + b3[1];
    }
}

// ---------------------------------------------------------------------------
// cp post: LN over [2,1024] + leaky + 2x softmax -> stdb (=102.4*s), wb
// ---------------------------------------------------------------------------
__global__ __launch_bounds__(256) void cp_post_k(const float* __restrict__ sw,
                                                 float* __restrict__ stdb,
                                                 float* __restrict__ wb)
{
    int b = blockIdx.x, tid = threadIdx.x;
    __shared__ float s0[1024], s1[1024], red[256];
    const float* p = sw + b * 2048;
    float s = 0.f, q = 0.f;
    for (int l = tid; l < 1024; l += 256) {
        float v0 = p[l], v1 = p[1024 + l];
        s0[l] = v0; s1[l] = v1;
        s += v0 + v1; q += v0 * v0 + v1 * v1;
    }
    red[tid] = s; __syncthreads();
    for (int o = 128; o; o >>= 1) { if (tid < o) red[tid] += red[tid + o]; __syncthreads(); }
    float mean = red[0] / 2048.f; __syncthreads();
    red[tid] = q; __syncthreads();
    for (int o = 128; o; o >>= 1) { if (tid < o) red[tid] += red[tid + o]; __syncthreads(); }
    float inv = rsqrtf(red[0] / 2048.f - mean * mean + EPS_LN); __syncthreads();
    for (int l = tid; l < 1024; l += 256) {
        s0[l] = leakyf((s0[l] - mean) * inv);
        s1[l] = leakyf((s1[l] - mean) * inv);
    }
    __syncthreads();
    float mx = -1e30f;
    for (int l = tid; l < 1024; l += 256) mx = fmaxf(mx, s0[l]);
    red[tid] = mx; __syncthreads();
    for (int o = 128; o; o >>= 1) { if (tid < o) red[tid] = fmaxf(red[tid], red[tid + o]); __syncthreads(); }
    mx = red[0]; __syncthreads();
    float se = 0.f;
    for (int l = tid; l < 1024; l += 256) { float e = __expf(s0[l] - mx); s0[l] = e; se += e; }
    red[tid] = se; __syncthreads();
    for (int o = 128; o; o >>= 1) { if (tid < o) red[tid] += red[tid + o]; __syncthreads(); }
    float rs = 1.f / red[0]; __syncthreads();
    for (int l = tid; l < 1024; l += 256) stdb[b * 1024 + l] = 102.4f * s0[l] * rs;
    mx = -1e30f;
    for (int l = tid; l < 1024; l += 256) mx = fmaxf(mx, s1[l]);
    red[tid] = mx; __syncthreads();
    for (int o = 128; o; o >>= 1) { if (tid < o) red[tid] = fmaxf(red[tid], red[tid + o]); __syncthreads(); }
    mx = red[0]; __syncthreads();
    se = 0.f;
    for (int l = tid; l < 1024; l += 256) { float e = __expf(s1[l] - mx); s1[l] = e; se += e; }
    red[tid] = se; __syncthreads();
    for (int o = 128; o; o >>= 1) { if (tid < o) red[tid] += red[tid + o]; __syncthreads(); }
    rs = 1.f / red[0]; __syncthreads();
    for (int l = tid; l < 1024; l += 256) wb[b * 1024 + l] = s1[l] * rs;
}

// ---------------------------------------------------------------------------
// pooling (radius-pruned Gaussian mix), writes Acat[:, :, 0:640] bf16
// ---------------------------------------------------------------------------
__global__ __launch_bounds__(256) void pool_k(const float* __restrict__ feats,
                                              const float* __restrict__ stdb,
                                              const float* __restrict__ wb,
                                              bf16* __restrict__ acat)
{
    int i = blockIdx.x, b = blockIdx.y, tid = threadIdx.x;
    float sd = stdb[b * 1024 + i];
    float den = 1e-5f + 2.f * sd * sd;
    float inv = 1.f / den;
    int R = (int)sqrtf(11.5129255f * den) + 1;
    int jlo = max(0, i - R), jhi = min(1023, i + R);
    __shared__ float cj[256];
    float a0 = 0.f, a1 = 0.f, a2 = 0.f;
    const float* fb = feats + (long)b * 1024 * 640;
    for (int j0 = jlo; j0 <= jhi; j0 += 256) {
        int j = j0 + tid;
        float c = 0.f;
        if (j <= jhi) {
            float d = (float)(j - i);
            c = __expf(-d * d * inv) * wb[b * 1024 + j];
        }
        __syncthreads();
        cj[tid] = c;
        __syncthreads();
        int lim = min(256, jhi - j0 + 1);
        for (int t = 0; t < lim; ++t) {
            float cc = cj[t];
            const float* fr = fb + (long)(j0 + t) * 640;
            a0 += cc * fr[tid];
            a1 += cc * fr[tid + 256];
            if (tid < 128) a2 += cc * fr[tid + 512];
        }
    }
    long obase = ((long)b * 1024 + i) * 1280;
    long fbase = ((long)b * 1024 + i) * 640;
    acat[obase + tid] = __float2bfloat16(a0 + feats[fbase + tid]);
    acat[obase + tid + 256] = __float2bfloat16(a1 + feats[fbase + tid + 256]);
    if (tid < 128) acat[obase + tid + 512] = __float2bfloat16(a2 + feats[fbase + tid + 512]);
}

// ---------------------------------------------------------------------------
__global__ void repack_w_k(const float* __restrict__ w, bf16* __restrict__ bt, int CO, int CI)
{
    long idx = (long)blockIdx.x * 256 + threadIdx.x;
    long total = (long)CO * CI * 3;
    if (idx >= total) return;
    int K3 = 3 * CI;
    int o = (int)(idx / K3);
    int k = (int)(idx % K3);
    int t = k / CI, ci = k % CI;
    bt[idx] = __float2bfloat16(w[(long)o * CI * 3 + ci * 3 + t]);
}

__global__ void cast_bf16_k(const float* __restrict__ w, bf16* __restrict__ o, long n)
{
    long idx = (long)blockIdx.x * 256 + threadIdx.x;
    if (idx < n) o[idx] = __float2bfloat16(w[idx]);
}

// ---------------------------------------------------------------------------
extern "C" void kernel_launch(void* const* d_in, const int* in_sizes, int n_in,
                              void* d_out, int out_size, void* d_ws, size_t ws_size,
                              hipStream_t stream)
{
    const float* feats = (const float*)d_in[0];
    const float* cp_w1 = (const float*)d_in[1];
    const float* cp_b1 = (const float*)d_in[2];
    const float* cp_w2 = (const float*)d_in[3];
    const float* cp_b2 = (const float*)d_in[4];
    const float* cp_w3 = (const float*)d_in[5];
    const float* cp_b3 = (const float*)d_in[6];
    const float* cv_w1 = (const float*)d_in[7];
    const float* cv_b1 = (const float*)d_in[8];
    const float* cv_w2 = (const float*)d_in[9];
    const float* cv_b2 = (const float*)d_in[10];
    const float* cv_w3 = (const float*)d_in[11];
    const float* cv_b3 = (const float*)d_in[12];
    const float* mlp_w = (const float*)d_in[13];
    const float* mlp_b = (const float*)d_in[14];
    float* out = (float*)d_out;

    char* ws = (char*)d_ws;
    size_t off = 0;
    auto alloc = [&](size_t bytes) -> char* {
        char* p = ws + off;
        off += (bytes + 255) & ~(size_t)255;
        return p;
    };
    bf16* XpadF = (bf16*)alloc(16L * 1026 * 640 * 2);
    bf16* Xpad2 = (bf16*)alloc(16L * 1026 * 1280 * 2);
    bf16* Ybf = (bf16*)alloc(16L * 1024 * 1280 * 2);
    bf16* Acat = (bf16*)alloc(16L * 1024 * 1280 * 2);
    bf16* Bcp1 = (bf16*)alloc(1280L * 1920 * 2);
    bf16* Bcp2 = (bf16*)alloc(1280L * 3840 * 2);
    bf16* Bcp3 = (bf16*)alloc(2L * 3840 * 2);
    bf16* Bcv1 = (bf16*)alloc(1280L * 1920 * 2);
    bf16* Bcv2 = (bf16*)alloc(1280L * 3840 * 2);
    bf16* Bcv3 = (bf16*)alloc(640L * 3840 * 2);
    bf16* Bmlp = (bf16*)alloc(640L * 1280 * 2);
    float* swb = (float*)alloc(16L * 2048 * 4);
    float* stdb = (float*)alloc(16L * 1024 * 4);
    float* wbf = (float*)alloc(16L * 1024 * 4);
    float2* sacc = (float2*)alloc(16L * 8);
    float2* stat = (float2*)alloc(16L * 8);
    (void)ws_size; (void)in_sizes; (void)n_in; (void)out_size;

    const long NF8 = 16L * 1026 * 640 / 8;
    const long N28 = 16L * 1026 * 1280 / 8;
    const long NA8 = 16L * 1024 * 640 / 8;
    const long N1280 = 1024L * 1280, N640 = 1024L * 640;
    const float inv1280 = 1.f / (float)N1280, inv640 = 1.f / (float)N640;

    pack_feats_v_k<<<(NF8 + 255) / 256, 256, 0, stream>>>(feats, XpadF, 640);
    repack_w_k<<<(1280L * 640 * 3 + 255) / 256, 256, 0, stream>>>(cp_w1, Bcp1, 1280, 640);
    repack_w_k<<<(1280L * 1280 * 3 + 255) / 256, 256, 0, stream>>>(cp_w2, Bcp2, 1280, 1280);
    repack_w_k<<<(2L * 1280 * 3 + 255) / 256, 256, 0, stream>>>(cp_w3, Bcp3, 2, 1280);
    repack_w_k<<<(1280L * 640 * 3 + 255) / 256, 256, 0, stream>>>(cv_w1, Bcv1, 1280, 640);
    repack_w_k<<<(1280L * 1280 * 3 + 255) / 256, 256, 0, stream>>>(cv_w2, Bcv2, 1280, 1280);
    repack_w_k<<<(640L * 1280 * 3 + 255) / 256, 256, 0, stream>>>(cv_w3, Bcv3, 640, 1280);
    cast_bf16_k<<<(640L * 1280 + 255) / 256, 256, 0, stream>>>(mlp_w, Bmlp, 640L * 1280);

    // ---- cp branch ----
    zero_stats_k<<<1, 64, 0, stream>>>(sacc);
    gemm_bf16<0><<<1280, 256, 0, stream>>>(XpadF, 1026L * 640, 640, Bcp1, cp_b1,
                                           Ybf, N1280, 1280, 1920, 10, 8, sacc);
    fin_k<<<1, 64, 0, stream>>>(sacc, stat, inv1280);
    norm_pack_v_k<<<(N28 + 255) / 256, 256, 0, stream>>>(Ybf, stat, Xpad2, 1280);
    zero_stats_k<<<1, 64, 0, stream>>>(sacc);
    gemm_bf16<0><<<1280, 256, 0, stream>>>(Xpad2, 1026L * 1280, 1280, Bcp2, cp_b2,
                                           Ybf, N1280, 1280, 3840, 10, 8, sacc);
    fin_k<<<1, 64, 0, stream>>>(sacc, stat, inv1280);
    norm_pack_v_k<<<(N28 + 255) / 256, 256, 0, stream>>>(Ybf, stat, Xpad2, 1280);
    conv3cp_k<<<4096, 256, 0, stream>>>(Xpad2, Bcp3, cp_b3, swb);
    cp_post_k<<<16, 256, 0, stream>>>(swb, stdb, wbf);
    pool_k<<<dim3(1024, 16), 256, 0, stream>>>(feats, stdb, wbf, Acat);

    // ---- cv branch ----
    zero_stats_k<<<1, 64, 0, stream>>>(sacc);
    gemm_bf16<0><<<1280, 256, 0, stream>>>(XpadF, 1026L * 640, 640, Bcv1, cv_b1,
                                           Ybf, N1280, 1280, 1920, 10, 8, sacc);
    fin_k<<<1, 64, 0, stream>>>(sacc, stat, inv1280);
    norm_pack_v_k<<<(N28 + 255) / 256, 256, 0, stream>>>(Ybf, stat, Xpad2, 1280);
    zero_stats_k<<<1, 64, 0, stream>>>(sacc);
    gemm_bf16<0><<<1280, 256, 0, stream>>>(Xpad2, 1026L * 1280, 1280, Bcv2, cv_b2,
                                           Ybf, N1280, 1280, 3840, 10, 8, sacc);
    fin_k<<<1, 64, 0, stream>>>(sacc, stat, inv1280);
    norm_pack_v_k<<<(N28 + 255) / 256, 256, 0, stream>>>(Ybf, stat, Xpad2, 1280);
    zero_stats_k<<<1, 64, 0, stream>>>(sacc);
    gemm_bf16<0><<<640, 256, 0, stream>>>(Xpad2, 1026L * 1280, 1280, Bcv3, cv_b3,
                                          Ybf, N640, 640, 3840, 5, 8, sacc);
    fin_k<<<1, 64, 0, stream>>>(sacc, stat, inv640);
    norm_addf_v_k<<<(NA8 + 255) / 256, 256, 0, stream>>>(Ybf, stat, feats, Acat);

    // ---- MLP ----
    gemm_bf16<1><<<640, 256, 0, stream>>>(Acat, N1280, 1280, Bmlp, mlp_b,
                                          out, N640, 640, 1280, 5, 8, nullptr);
}